// Round 8
// baseline (503.834 us; speedup 1.0000x reference)
//
#include <hip/hip_runtime.h>
#include <cmath>

// Problem constants
#define Bb 256
#define Ss 50
#define Cc 40
#define Dd 256
#define Vv 20000

typedef __bf16 bf16;
typedef __bf16 bf16x8 __attribute__((ext_vector_type(8)));
typedef float f32x4 __attribute__((ext_vector_type(4)));
typedef unsigned long long u64;

#define GL2LDS(g, l) __builtin_amdgcn_global_load_lds( \
    (__attribute__((address_space(1))) void*)(g), \
    (__attribute__((address_space(3))) void*)(l), 16, 0, 0)

// ---------------- ws layout (BYTE offsets) ----------------
// xch parity-0 uses the old BAR region (256 KB); xch parity-1 borrows the
// first 256 KB of the W region (wbuf is only written AFTER the recurrence).
#define OFFB_GATES    0ull
#define OFFB_ALIGNED  0ull
#define OFFB_CAT      13107200ull
#define OFFB_TMPB     25952256ull
#define OFFB_H1       32505856ull
#define OFFB_ATTNW    35717120ull
#define OFFB_X        52428800ull
#define OFFB_XB       65536000ull
#define OFFB_RNNB     72089600ull
#define OFFB_W        78643200ull
#define OFFB_XCH0     91750400ull
#define OFFB_WIHB     92012544ull
#define OFFB_WHHB     92536832ull
#define OFFB_WHKB     93061120ull
#define OFFB_W1B      93192192ull
#define OFFB_WDTB     93257728ull
#define OFFB_SALPHA   93388800ull
#define OFFB_SBETA    93389824ull

// ---------------- bf16 MFMA GEMM ----------------
template<int BM, int BN, int ACT>
__global__ __launch_bounds__(256) void mfma_gemm(
    const bf16* __restrict__ A, int lda,
    const bf16* __restrict__ B, int ldb,
    const float* __restrict__ bias1, const float* __restrict__ bias2,
    float* __restrict__ C, int ldc, int K)
{
    constexpr int BK = 32;
    constexpr int NF = BN / 32;           // n-frags per wave (2x2 wave grid)
    __shared__ bf16 As[BM * BK];
    __shared__ bf16 Bs[BN * BK];
    const int tid  = threadIdx.x;
    const int wave = tid >> 6;
    const int lane = tid & 63;
    const int m0 = blockIdx.x * BM;
    const int n0 = blockIdx.y * BN;
    const int wm = (wave >> 1) * 64;      // wave row offset in tile
    const int wn = (wave & 1) * (BN / 2); // wave col offset in tile

    f32x4 acc[4][NF];
#pragma unroll
    for (int i = 0; i < 4; ++i)
#pragma unroll
        for (int j = 0; j < NF; ++j) acc[i][j] = (f32x4){0.f, 0.f, 0.f, 0.f};

    const int ar = tid >> 2;              // staging row (0..63) within iter
    const int ac = tid & 3;               // staging chunk
    const int sw = ac ^ (ar & 3);         // swizzled source chunk
    const int lr = lane & 15;
    const int q  = lane >> 4;             // k-chunk of fragment

    for (int k0 = 0; k0 < K; k0 += BK) {
        __syncthreads();
#pragma unroll
        for (int it = 0; it < BM / 64; ++it) {
            const bf16* gp = A + (size_t)(m0 + it * 64 + ar) * lda + k0 + sw * 8;
            GL2LDS(gp, As + it * 2048 + wave * 512);
        }
#pragma unroll
        for (int it = 0; it < BN / 64; ++it) {
            const bf16* gp = B + (size_t)(n0 + it * 64 + ar) * ldb + k0 + sw * 8;
            GL2LDS(gp, Bs + it * 2048 + wave * 512);
        }
        __syncthreads();

        bf16x8 af[4], bfv[NF];
#pragma unroll
        for (int fm = 0; fm < 4; ++fm) {
            int m = wm + fm * 16 + lr;
            af[fm] = *(const bf16x8*)(As + m * 32 + ((q ^ (m & 3)) * 8));
        }
#pragma unroll
        for (int fn = 0; fn < NF; ++fn) {
            int n = wn + fn * 16 + lr;
            bfv[fn] = *(const bf16x8*)(Bs + n * 32 + ((q ^ (n & 3)) * 8));
        }
#pragma unroll
        for (int fm = 0; fm < 4; ++fm)
#pragma unroll
            for (int fn = 0; fn < NF; ++fn)
                acc[fm][fn] = __builtin_amdgcn_mfma_f32_16x16x32_bf16(
                    af[fm], bfv[fn], acc[fm][fn], 0, 0, 0);
    }

    // epilogue: C/D layout col=lane&15, row=(lane>>4)*4+reg
    const int rbase = q * 4;
#pragma unroll
    for (int fn = 0; fn < NF; ++fn) {
        const int col = n0 + wn + fn * 16 + lr;
        float bb = 0.f;
        if (bias1) bb += bias1[col];
        if (bias2) bb += bias2[col];
#pragma unroll
        for (int fm = 0; fm < 4; ++fm) {
            f32x4 v = acc[fm][fn];
#pragma unroll
            for (int r = 0; r < 4; ++r) {
                const int row = m0 + wm + fm * 16 + rbase + r;
                float val = v[r] + bb;
                if (ACT == 1) val = tanhf(val);
                C[(size_t)row * ldc + col] = val;
            }
        }
    }
}

// ---------------- fused LSTM recurrence: tagged one-RT exchange ------------
// 64 blocks x 512 threads. Block (bm = blockIdx&15, bd = blockIdx>>4):
// batch rows bm*16..+15, hidden quarter [bd*64,+64). Wave w: kh = w>>2
// (K-half), ct = w&3 (16-col tile); weights 4x4 frags = 64 VGPR (resident,
// r7 VGPR=88). kh=1 partials via padded pacc (r7's [16][16] was a 4-way
// bank conflict: 1.25M SQ_LDS_BANK_CONFLICT); kh=0 combines + elementwise.
// EXCHANGE (the r4-r7 ~3.4us/step floor was TWO dependent LLC round trips:
// flag-visible then data-load, plus a vmcnt(0) drain): each h value is sent
// as u32 (tag<<16)|bf16, tag = t+1, via relaxed agent-scope atomic stores
// into a parity-double-buffered exchange array. Consumers poll the DATA
// WORDS directly until the tag matches -> ONE round trip, no flag, no B2
// drain barrier. ABA safe: producer cannot lap a consumer by 2 steps
// (its T+2 send transitively requires the consumer's T recv). Stale tags
// across launches killed by prep zeroing both parities. rnnb gets plain
// cached stores (read only by later kernels; kernel-end flush suffices).
__global__ __launch_bounds__(512, 2) void lstm_quad(
    const bf16* __restrict__ Whhb,    // (1024 x 256) N x K
    const float* __restrict__ gates,  // (B*S x 1024) x@Wih^T+bih+bhh
    bf16* __restrict__ rnnb,          // (B*S x 256) h outputs
    unsigned* __restrict__ xch0,      // 64Ki u32: even-step exchange
    unsigned* __restrict__ xch1)      // 64Ki u32: odd-step exchange
{
    __shared__ bf16 hb0[16 * 256];
    __shared__ bf16 hb1[16 * 256];
    __shared__ float pacc[4][4][16][17];   // padded: kills 4-way conflicts
    const int tid  = threadIdx.x;
    const int w    = tid >> 6;
    const int lane = tid & 63;
    const int lr   = lane & 15;
    const int q    = lane >> 4;
    const int bm   = blockIdx.x & 15;
    const int bd   = blockIdx.x >> 4;       // 0..3
    const int kh   = w >> 2;                // K-half
    const int ct   = w & 3;                 // col tile
    const int dg   = bd * 64 + ct * 16 + lr;

    // ---- loop-invariant Whh fragments for this K-half: 64 VGPR ----
    f32x4 wfr[4][4];
#pragma unroll
    for (int g = 0; g < 4; ++g) {
        const bf16* brow = Whhb + (size_t)(g * 256 + dg) * Dd + kh * 128 + q * 8;
#pragma unroll
        for (int kc = 0; kc < 4; ++kc)
            wfr[g][kc] = *(const f32x4*)(brow + kc * 32);
    }

    // gate-preact pointers (kh=0 lanes): rows q*4+r, col dg
    const float* gp[4];
#pragma unroll
    for (int r = 0; r < 4; ++r)
        gp[r] = gates + (size_t)(bm * 16 + q * 4 + r) * (Ss * 1024) + dg;

    const int myslot = (bm * 4 + bd) << 10;   // this block's 1024-word slot

    // rnnb pack role (tid < 256): 8 B = 4 cols of one row
    const int xrow = tid >> 4, xc8 = tid & 15;
    const size_t my_base = ((size_t)(bm * 16 + xrow) * Ss) * Dd + bd * 64 + xc8 * 4;
    const int pack_off = xrow * 512 + (((bd * 8 + (xc8 >> 1)) ^ (xrow & 7)) << 4) + (xc8 & 1) * 8;

    // elementwise LDS write offsets (kh=0 lanes): row q*4+r, col dg
    int ew_off[4];
#pragma unroll
    for (int r = 0; r < 4; ++r) {
        const int row = q * 4 + r;
        ew_off[r] = row * 512 + (((dg >> 3) ^ (row & 7)) << 4) + (dg & 7) * 2;
    }

    float c[4] = {0.f, 0.f, 0.f, 0.f};
    float gaA[4][4], gaB[4][4];   // [gate][r], double-buffered preacts
    if (kh == 0) {
#pragma unroll
        for (int r = 0; r < 4; ++r)
#pragma unroll
            for (int g = 0; g < 4; ++g) gaA[g][r] = gp[r][g * 256];
    }

#define STEP(T, GACUR, GANEXT, RD, WR, XB, FIRST)                               \
    {                                                                           \
        f32x4 acc[4];                                                           \
        _Pragma("unroll")                                                       \
        for (int g = 0; g < 4; ++g) acc[g] = (f32x4){0.f, 0.f, 0.f, 0.f};       \
        if (!(FIRST)) {                                                         \
            bf16x8 af[4];                                                       \
            _Pragma("unroll")                                                   \
            for (int kc = 0; kc < 4; ++kc)                                      \
                af[kc] = *(const bf16x8*)((const char*)(RD) + lr * 512          \
                         + (((kh * 16 + kc * 4 + q) ^ (lr & 7)) << 4));         \
            _Pragma("unroll")                                                   \
            for (int kc = 0; kc < 4; ++kc)                                      \
                _Pragma("unroll")                                               \
                for (int g = 0; g < 4; ++g)                                     \
                    acc[g] = __builtin_amdgcn_mfma_f32_16x16x32_bf16(           \
                        af[kc], __builtin_bit_cast(bf16x8, wfr[g][kc]),         \
                        acc[g], 0, 0, 0);                                       \
        }                                                                       \
        if (kh == 1) {                                                          \
            _Pragma("unroll")                                                   \
            for (int g = 0; g < 4; ++g)                                         \
                _Pragma("unroll")                                               \
                for (int r = 0; r < 4; ++r)                                     \
                    pacc[ct][g][q * 4 + r][lr] = acc[g][r];                     \
        }                                                                       \
        __syncthreads();  /* Ba: kh1 partials visible */                        \
        if (kh == 0) {                                                          \
            _Pragma("unroll")                                                   \
            for (int r = 0; r < 4; ++r) {                                       \
                float gi = acc[0][r] + pacc[ct][0][q * 4 + r][lr] + GACUR[0][r];\
                float gf = acc[1][r] + pacc[ct][1][q * 4 + r][lr] + GACUR[1][r];\
                float gg = acc[2][r] + pacc[ct][2][q * 4 + r][lr] + GACUR[2][r];\
                float go = acc[3][r] + pacc[ct][3][q * 4 + r][lr] + GACUR[3][r];\
                float ii  = 1.f / (1.f + expf(-gi));                            \
                float ff  = 1.f / (1.f + expf(-gf));                            \
                float g2t = tanhf(gg);                                          \
                float oo  = 1.f / (1.f + expf(-go));                            \
                c[r] = ff * c[r] + ii * g2t;                                    \
                *(bf16*)((char*)(WR) + ew_off[r]) = (bf16)(oo * tanhf(c[r]));   \
            }                                                                   \
        }                                                                       \
        __syncthreads();  /* B1: local h quarter in LDS */                      \
        {   /* send: 2 tagged u32 per thread, one LLC store each */            \
            const unsigned tg = (unsigned)((T) + 1) << 16;                      \
            _Pragma("unroll")                                                   \
            for (int s = 0; s < 2; ++s) {                                       \
                const int widx = tid * 2 + s;                                   \
                const int row = widx >> 6, col = widx & 63;                     \
                const int dgs = bd * 64 + col;                                  \
                const int off = row * 512 + (((dgs >> 3) ^ (row & 7)) << 4)     \
                                + (dgs & 7) * 2;                                \
                unsigned short hv =                                             \
                    *(const unsigned short*)((const char*)(WR) + off);          \
                __hip_atomic_store((XB) + myslot + widx, tg | (unsigned)hv,     \
                                   __ATOMIC_RELAXED, __HIP_MEMORY_SCOPE_AGENT); \
            }                                                                   \
        }                                                                       \
        if (tid < 256) {  /* plain cached store of h quarter to rnnb */         \
            u64 v = *(const u64*)((const char*)(WR) + pack_off);                \
            *(u64*)(rnnb + my_base + (size_t)(T) * Dd) = v;                     \
        }                                                                       \
        if ((T) != Ss - 1) {                                                    \
            if (kh == 0) {  /* preact prefetch hides under the poll */          \
                _Pragma("unroll")                                               \
                for (int r = 0; r < 4; ++r)                                     \
                    _Pragma("unroll")                                           \
                    for (int g = 0; g < 4; ++g)                                 \
                        GANEXT[g][r] = gp[r][(size_t)((T) + 1) * 1024 + g * 256];\
            }                                                                   \
            {   /* recv: poll 6 tagged words (3 partner quarters) */            \
                const unsigned tv = (unsigned)((T) + 1);                        \
                _Pragma("unroll")                                               \
                for (int j = 0; j < 6; ++j) {                                   \
                    const int rr = tid * 6 + j;                                 \
                    const int p_ = rr >> 10, w2 = rr & 1023;                    \
                    const int pd_ = p_ + (p_ >= bd ? 1 : 0);                    \
                    const int row = w2 >> 6, col = w2 & 63;                     \
                    const int dgp = pd_ * 64 + col;                             \
                    unsigned v;                                                 \
                    do {                                                        \
                        v = __hip_atomic_load((XB) + ((bm * 4 + pd_) << 10) + w2,\
                                __ATOMIC_RELAXED, __HIP_MEMORY_SCOPE_AGENT);    \
                    } while ((v >> 16) != tv);                                  \
                    const int off = row * 512 + (((dgp >> 3) ^ (row & 7)) << 4) \
                                    + (dgp & 7) * 2;                            \
                    *(unsigned short*)((char*)(WR) + off) = (unsigned short)v;  \
                }                                                               \
            }                                                                   \
            __syncthreads();  /* B4: full h_t (local + 3 remote) in WR */       \
        }                                                                       \
    }

    for (int t2 = 0; t2 < Ss; t2 += 2) {
        // even step: WR=hb0, RD=hb1, exchange parity 0
        STEP(t2,     gaA, gaB, hb1, hb0, xch0, (t2 == 0));
        // odd step: WR=hb1, RD=hb0, exchange parity 1
        STEP(t2 + 1, gaB, gaA, hb0, hb1, xch1, false);
    }
#undef STEP
}

// ---------------- fused prep: weight converts + transpose + zero + alpha ---
// Blocks: [0,1024) Wih | [1024,2048) Whh | [2048,2304) Whk | [2304,2432) W1 |
// [2432,2496) Wdiff transpose | [2496,2752) zero xch0 | [2752,3008) zero xch1
// | 3008 alpha
__global__ __launch_bounds__(256) void prep_kernel(
    const float* __restrict__ Wih, bf16* __restrict__ Wihb,
    const float* __restrict__ Whh, bf16* __restrict__ Whhb,
    const float* __restrict__ Whk, bf16* __restrict__ Whkb,
    const float* __restrict__ W1,  bf16* __restrict__ W1b,
    const float* __restrict__ Wdiff, bf16* __restrict__ WdTb,
    const int* __restrict__ tdiff, float* __restrict__ salpha,
    float* __restrict__ sbeta,
    unsigned* __restrict__ xch0, unsigned* __restrict__ xch1)
{
    __shared__ float t[32][33];
    int bx = blockIdx.x;
    const int tid = threadIdx.x;
    if (bx < 1024) { int i = bx * 256 + tid; Wihb[i] = (bf16)Wih[i]; return; }
    bx -= 1024;
    if (bx < 1024) { int i = bx * 256 + tid; Whhb[i] = (bf16)Whh[i]; return; }
    bx -= 1024;
    if (bx < 256)  { int i = bx * 256 + tid; Whkb[i] = (bf16)Whk[i]; return; }
    bx -= 256;
    if (bx < 128)  { int i = bx * 256 + tid; W1b[i]  = (bf16)W1[i];  return; }
    bx -= 128;
    if (bx < 64) {
        const int c0 = (bx & 7) * 32, r0 = (bx >> 3) * 32;
        const int tx = tid & 31, ty = tid >> 5;
        for (int i = ty; i < 32; i += 8)
            t[i][tx] = Wdiff[(size_t)(r0 + i) * 256 + c0 + tx];
        __syncthreads();
        for (int i = ty; i < 32; i += 8)
            WdTb[(size_t)(c0 + i) * 256 + r0 + tx] = (bf16)t[tx][i];
        return;
    }
    bx -= 64;
    if (bx < 256) { xch0[bx * 256 + tid] = 0u; return; }
    bx -= 256;
    if (bx < 256) { xch1[bx * 256 + tid] = 0u; return; }
    // alpha
    const int tt = tdiff[tid];
    const float step = (0.02f - 1e-4f) / 999.f;
    float prod = 1.f;
    for (int j = 0; j <= tt; ++j) prod *= (1.f - (1e-4f + j * step));
    salpha[tid] = sqrtf(prod);
    sbeta[tid]  = sqrtf(fmaxf(1.f - prod, 0.f));
}

// ---------------- embedding gather-sum (fp32 + bf16 outputs) ----------------
__global__ __launch_bounds__(256) void embed_kernel(
    const int* __restrict__ seqs, const float* __restrict__ emb,
    float* __restrict__ x, bf16* __restrict__ xb)
{
    __shared__ int idx[Cc];
    const int bs = blockIdx.x;
    const int tid = threadIdx.x;
    if (tid < Cc) idx[tid] = seqs[(size_t)bs * Cc + tid];
    __syncthreads();
    float s = 0.f;
#pragma unroll 8
    for (int c = 0; c < Cc; ++c) s += emb[(size_t)idx[c] * Dd + tid];
    x[(size_t)bs * Dd + tid]  = s;
    xb[(size_t)bs * Dd + tid] = (bf16)s;
}

// ---------------- attention: cat build (bf16), logits ----------------
__global__ __launch_bounds__(256) void cat_build_kernel(
    const float* __restrict__ x, const float* __restrict__ w, bf16* __restrict__ cat)
{
    const int r = blockIdx.x;             // b*49+t
    const int b = r / (Ss - 1), t = r % (Ss - 1);
    const int d = threadIdx.x;
    cat[(size_t)r * 512 + d]       = (bf16)x[((size_t)b * Ss) * Dd + d];
    cat[(size_t)r * 512 + 256 + d] = (bf16)w[((size_t)b * Ss + t) * Dd + d];
}

__global__ __launch_bounds__(256) void attn2_kernel(
    const float* __restrict__ H1, const float* __restrict__ W2,
    const float* __restrict__ b2, float* __restrict__ attnw)
{
    const int r = blockIdx.x * 4 + (threadIdx.x >> 6);
    const int j = threadIdx.x & 63;
    float h = H1[(size_t)r * 64 + j];
    float v0 = h * W2[j];
    float v1 = h * W2[64 + j];
#pragma unroll
    for (int off = 32; off; off >>= 1) { v0 += __shfl_down(v0, off); v1 += __shfl_down(v1, off); }
    if (j == 0) {
        float z0 = v0 + b2[0], z1 = v1 + b2[1];
        float m = fmaxf(z0, z1);
        float e0 = expf(z0 - m), e1 = expf(z1 - m);
        float inv = 1.f / (e0 + e1);
        attnw[(size_t)r * 2 + 0] = e0 * inv;
        attnw[(size_t)r * 2 + 1] = e1 * inv;
    }
}

// ---------------- fused attn-apply + diffusion elementwise ----------------
__global__ __launch_bounds__(256) void attn_diff_kernel(
    const float* __restrict__ x, const float* __restrict__ w,
    const float* __restrict__ attnw, const float* __restrict__ noise,
    const float* __restrict__ temb, const int* __restrict__ tdiff,
    const float* __restrict__ salpha, const float* __restrict__ sbeta,
    float* __restrict__ aligned, bf16* __restrict__ tmpb)
{
    const int bs = blockIdx.x;
    const int b = bs / Ss, s = bs % Ss;
    const int d = threadIdx.x;
    const float ek = x[((size_t)b * Ss) * Dd + d];
    float v;
    if (s == 0) {
        v = ek;
    } else {
        const int r = b * (Ss - 1) + (s - 1);
        const float a0 = attnw[(size_t)r * 2], a1 = attnw[(size_t)r * 2 + 1];
        v = ek * a0 + w[((size_t)b * Ss + s - 1) * Dd + d] * a1;
    }
    const size_t i = (size_t)bs * Dd + d;
    aligned[i] = v;
    const int t = tdiff[b];
    tmpb[i] = (bf16)(v * salpha[b] + noise[i] * sbeta[b] + temb[(size_t)t * Dd + d]);
}

// ---------------- pooled 2-class heads ----------------
__device__ inline void pool_reduce_write(float m, const float* __restrict__ Wout,
                                         const float* __restrict__ bout,
                                         float* __restrict__ outp, int b,
                                         float* r0, float* r1)
{
    float v0 = m * Wout[threadIdx.x];
    float v1 = m * Wout[Dd + threadIdx.x];
#pragma unroll
    for (int off = 32; off; off >>= 1) { v0 += __shfl_down(v0, off); v1 += __shfl_down(v1, off); }
    const int lane = threadIdx.x & 63, wv = threadIdx.x >> 6;
    if (lane == 0) { r0[wv] = v0; r1[wv] = v1; }
    __syncthreads();
    if (threadIdx.x == 0) {
        outp[b * 2 + 0] = r0[0] + r0[1] + r0[2] + r0[3] + bout[0];
        outp[b * 2 + 1] = r1[0] + r1[1] + r1[2] + r1[3] + bout[1];
    }
}

__global__ __launch_bounds__(256) void pool_x_kernel(
    const float* __restrict__ x, const float* __restrict__ Wout,
    const float* __restrict__ bout, float* __restrict__ outp)
{
    __shared__ float r0[4], r1[4];
    const int b = blockIdx.x, d = threadIdx.x;
    float m = -INFINITY;
    for (int s = 0; s < Ss; ++s) m = fmaxf(m, x[((size_t)b * Ss + s) * Dd + d]);
    pool_reduce_write(m, Wout, bout, outp, b, r0, r1);
}

__global__ __launch_bounds__(256) void gen_pool_kernel(
    const float* __restrict__ aligned, const float* __restrict__ noise,
    const float* __restrict__ pred, const float* __restrict__ Wout,
    const float* __restrict__ bout, float* __restrict__ outp)
{
    __shared__ float r0[4], r1[4];
    const int b = blockIdx.x, d = threadIdx.x;
    float m = -INFINITY;
    for (int s = 0; s < Ss; ++s) {
        const size_t i = ((size_t)b * Ss + s) * Dd + d;
        m = fmaxf(m, aligned[i] + noise[i] - pred[i]);
    }
    pool_reduce_write(m, Wout, bout, outp, b, r0, r1);
}

// ---------------- host ----------------
extern "C" void kernel_launch(void* const* d_in, const int* in_sizes, int n_in,
                              void* d_out, int out_size, void* d_ws, size_t ws_size,
                              hipStream_t stream)
{
    const int*   seqs  = (const int*)d_in[0];
    const int*   tdiff = (const int*)d_in[5];
    const float* noise = (const float*)d_in[6];
    const float* emb   = (const float*)d_in[7];
    const float* Wih   = (const float*)d_in[8];
    const float* Whh   = (const float*)d_in[9];
    const float* bih   = (const float*)d_in[10];
    const float* bhh   = (const float*)d_in[11];
    const float* Whk   = (const float*)d_in[12];
    const float* bhk   = (const float*)d_in[13];
    const float* W1    = (const float*)d_in[14];
    const float* b1    = (const float*)d_in[15];
    const float* W2    = (const float*)d_in[16];
    const float* b2    = (const float*)d_in[17];
    const float* Wdiff = (const float*)d_in[18];
    const float* bdiff = (const float*)d_in[19];
    const float* temb  = (const float*)d_in[20];
    const float* Wout  = (const float*)d_in[21];
    const float* bout  = (const float*)d_in[22];

    float* outp = (float*)d_out;
    char*  wsb  = (char*)d_ws;

    float* gates   = (float*)(wsb + OFFB_GATES);
    float* aligned = (float*)(wsb + OFFB_ALIGNED);
    bf16*  catb    = (bf16*) (wsb + OFFB_CAT);
    bf16*  tmpb    = (bf16*) (wsb + OFFB_TMPB);
    float* H1      = (float*)(wsb + OFFB_H1);
    float* attnw   = (float*)(wsb + OFFB_ATTNW);
    float* x       = (float*)(wsb + OFFB_X);
    bf16*  xb      = (bf16*) (wsb + OFFB_XB);
    bf16*  rnnb    = (bf16*) (wsb + OFFB_RNNB);
    float* wbuf    = (float*)(wsb + OFFB_W);
    unsigned* xch0 = (unsigned*)(wsb + OFFB_XCH0);
    unsigned* xch1 = (unsigned*)(wsb + OFFB_W);     // borrows wbuf head
    bf16*  Wihb    = (bf16*) (wsb + OFFB_WIHB);
    bf16*  Whhb    = (bf16*) (wsb + OFFB_WHHB);
    bf16*  Whkb    = (bf16*) (wsb + OFFB_WHKB);
    bf16*  W1b     = (bf16*) (wsb + OFFB_W1B);
    bf16*  WdTb    = (bf16*) (wsb + OFFB_WDTB);
    float* salpha  = (float*)(wsb + OFFB_SALPHA);
    float* sbeta   = (float*)(wsb + OFFB_SBETA);

    float* pred_out  = outp + 1024;                        // (B,S,D)
    float* noise_out = outp + 1024 + (size_t)Bb * Ss * Dd; // (B,S,D)

    // fused prep: converts + transpose + exchange-buffer zero + alpha
    prep_kernel<<<3009, 256, 0, stream>>>(Wih, Wihb, Whh, Whhb, Whk, Whkb,
                                          W1, W1b, Wdiff, WdTb,
                                          tdiff, salpha, sbeta, xch0, xch1);

    // x = emb[seqs].sum(axis=2)  (fp32 + bf16)
    embed_kernel<<<Bb * Ss, 256, 0, stream>>>(seqs, emb, x, xb);

    // pool_x head (only needs x)
    pool_x_kernel<<<Bb, 256, 0, stream>>>(x, Wout, bout, outp);

    // gates_pre = x @ Wih^T + bih + bhh : (12800 x 1024), K=256
    mfma_gemm<128, 128, 0><<<dim3(100, 8), 256, 0, stream>>>(
        xb, 256, Wihb, 256, bih, bhh, gates, 1024, 256);

    // LSTM recurrence: ONE launch, 64 blocks, tagged one-RT exchange
    lstm_quad<<<64, 512, 0, stream>>>(Whhb, gates, rnnb, xch0, xch1);

    // w = rnn @ Whk^T + bhk : (12800 x 256), K=256  (overwrites xch1 region)
    mfma_gemm<128, 128, 0><<<dim3(100, 2), 256, 0, stream>>>(
        rnnb, 256, Whkb, 256, bhk, nullptr, wbuf, 256, 256);

    // attention MLP
    cat_build_kernel<<<Bb * (Ss - 1), 256, 0, stream>>>(x, wbuf, catb);
    // H1 = tanh(cat @ W1^T + b1) : (12544 x 64), K=512
    mfma_gemm<128, 64, 1><<<dim3(98, 1), 256, 0, stream>>>(
        catb, 512, W1b, 512, b1, nullptr, H1, 64, 512);
    attn2_kernel<<<(Bb * (Ss - 1)) / 4, 256, 0, stream>>>(H1, W2, b2, attnw);

    // fused: aligned = attn-apply(x,w,attnw); tmp = diffusion(aligned,...)
    attn_diff_kernel<<<Bb * Ss, 256, 0, stream>>>(
        x, wbuf, attnw, noise, temb, tdiff, salpha, sbeta, aligned, tmpb);

    // predicted_noise = tmp @ Wdiff + bdiff -> d_out
    mfma_gemm<128, 128, 0><<<dim3(100, 2), 256, 0, stream>>>(
        tmpb, 256, WdTb, 256, bdiff, nullptr, pred_out, 256, 256);

    // gen_pool head: max_s(aligned + noise - pred) @ Wout^T + bout
    gen_pool_kernel<<<Bb, 256, 0, stream>>>(aligned, noise, pred_out, Wout, bout, outp + 512);

    // normal_noise passthrough
    hipMemcpyAsync(noise_out, noise, (size_t)Bb * Ss * Dd * sizeof(float),
                   hipMemcpyDeviceToDevice, stream);
}

// Round 9
// 480.382 us; speedup vs baseline: 1.0488x; 1.0488x over previous
//
#include <hip/hip_runtime.h>
#include <cmath>

// Problem constants
#define Bb 256
#define Ss 50
#define Cc 40
#define Dd 256
#define Vv 20000

typedef __bf16 bf16;
typedef __bf16 bf16x8 __attribute__((ext_vector_type(8)));
typedef float f32x4 __attribute__((ext_vector_type(4)));
typedef unsigned long long u64;

#define GL2LDS(g, l) __builtin_amdgcn_global_load_lds( \
    (__attribute__((address_space(1))) void*)(g), \
    (__attribute__((address_space(3))) void*)(l), 16, 0, 0)

// ---------------- ws layout (BYTE offsets) ----------------
// CAT region is repurposed as wbb (bf16 copy of w, 6.5 MB) — cat_build is gone.
#define OFFB_GATES    0ull
#define OFFB_ALIGNED  0ull
#define OFFB_WBB      13107200ull
#define OFFB_TMPB     25952256ull
#define OFFB_H1       32505856ull
#define OFFB_X        52428800ull
#define OFFB_XB       65536000ull
#define OFFB_RNNB     72089600ull
#define OFFB_W        78643200ull
#define OFFB_BAR      91750400ull
#define OFFB_WIHB     92012544ull
#define OFFB_WHHB     92536832ull
#define OFFB_WHKB     93061120ull
#define OFFB_W1B      93192192ull
#define OFFB_WDTB     93257728ull
#define OFFB_SALPHA   93388800ull
#define OFFB_SBETA    93389824ull

// ---------------- bf16 MFMA GEMM (optional extra bf16 output Cb) ----------
template<int BM, int BN, int ACT>
__global__ __launch_bounds__(256) void mfma_gemm(
    const bf16* __restrict__ A, int lda,
    const bf16* __restrict__ B, int ldb,
    const float* __restrict__ bias1, const float* __restrict__ bias2,
    float* __restrict__ C, bf16* __restrict__ Cb, int ldc, int K)
{
    constexpr int BK = 32;
    constexpr int NF = BN / 32;           // n-frags per wave (2x2 wave grid)
    __shared__ bf16 As[BM * BK];
    __shared__ bf16 Bs[BN * BK];
    const int tid  = threadIdx.x;
    const int wave = tid >> 6;
    const int lane = tid & 63;
    const int m0 = blockIdx.x * BM;
    const int n0 = blockIdx.y * BN;
    const int wm = (wave >> 1) * 64;      // wave row offset in tile
    const int wn = (wave & 1) * (BN / 2); // wave col offset in tile

    f32x4 acc[4][NF];
#pragma unroll
    for (int i = 0; i < 4; ++i)
#pragma unroll
        for (int j = 0; j < NF; ++j) acc[i][j] = (f32x4){0.f, 0.f, 0.f, 0.f};

    const int ar = tid >> 2;              // staging row (0..63) within iter
    const int ac = tid & 3;               // staging chunk
    const int sw = ac ^ (ar & 3);         // swizzled source chunk
    const int lr = lane & 15;
    const int q  = lane >> 4;             // k-chunk of fragment

    for (int k0 = 0; k0 < K; k0 += BK) {
        __syncthreads();
#pragma unroll
        for (int it = 0; it < BM / 64; ++it) {
            const bf16* gp = A + (size_t)(m0 + it * 64 + ar) * lda + k0 + sw * 8;
            GL2LDS(gp, As + it * 2048 + wave * 512);
        }
#pragma unroll
        for (int it = 0; it < BN / 64; ++it) {
            const bf16* gp = B + (size_t)(n0 + it * 64 + ar) * ldb + k0 + sw * 8;
            GL2LDS(gp, Bs + it * 2048 + wave * 512);
        }
        __syncthreads();

        bf16x8 af[4], bfv[NF];
#pragma unroll
        for (int fm = 0; fm < 4; ++fm) {
            int m = wm + fm * 16 + lr;
            af[fm] = *(const bf16x8*)(As + m * 32 + ((q ^ (m & 3)) * 8));
        }
#pragma unroll
        for (int fn = 0; fn < NF; ++fn) {
            int n = wn + fn * 16 + lr;
            bfv[fn] = *(const bf16x8*)(Bs + n * 32 + ((q ^ (n & 3)) * 8));
        }
#pragma unroll
        for (int fm = 0; fm < 4; ++fm)
#pragma unroll
            for (int fn = 0; fn < NF; ++fn)
                acc[fm][fn] = __builtin_amdgcn_mfma_f32_16x16x32_bf16(
                    af[fm], bfv[fn], acc[fm][fn], 0, 0, 0);
    }

    // epilogue: C/D layout col=lane&15, row=(lane>>4)*4+reg
    const int rbase = q * 4;
#pragma unroll
    for (int fn = 0; fn < NF; ++fn) {
        const int col = n0 + wn + fn * 16 + lr;
        float bb = 0.f;
        if (bias1) bb += bias1[col];
        if (bias2) bb += bias2[col];
#pragma unroll
        for (int fm = 0; fm < 4; ++fm) {
            f32x4 v = acc[fm][fn];
#pragma unroll
            for (int r = 0; r < 4; ++r) {
                const int row = m0 + wm + fm * 16 + rbase + r;
                float val = v[r] + bb;
                if (ACT == 1) val = tanhf(val);
                C[(size_t)row * ldc + col] = val;
                if (Cb) Cb[(size_t)row * ldc + col] = (bf16)val;
            }
        }
    }
}

// ---------------- H1 GEMM with fused cat construction ----------------------
// H1 = tanh(cat @ W1^T + b1), cat row r=(b,t): cols [0,256) = x[b,0,:],
// cols [256,512) = w[b,t,:]. A-tile staged directly from xb / wbb (bf16,
// identical rounding to the old cat_build) -> cat is never materialized.
__global__ __launch_bounds__(256) void h1_gemm(
    const bf16* __restrict__ xb, const bf16* __restrict__ wbb,
    const bf16* __restrict__ W1b,
    const float* __restrict__ b1, float* __restrict__ H1)
{
    constexpr int BM = 128, BN = 64, BK = 32, NF = 2;
    constexpr int K = 512;
    __shared__ bf16 As[BM * BK];
    __shared__ bf16 Bs[BN * BK];
    const int tid  = threadIdx.x;
    const int wave = tid >> 6;
    const int lane = tid & 63;
    const int m0 = blockIdx.x * BM;
    const int wm = (wave >> 1) * 64;
    const int wn = (wave & 1) * 32;

    f32x4 acc[4][NF];
#pragma unroll
    for (int i = 0; i < 4; ++i)
#pragma unroll
        for (int j = 0; j < NF; ++j) acc[i][j] = (f32x4){0.f, 0.f, 0.f, 0.f};

    const int ar = tid >> 2;
    const int ac = tid & 3;
    const int sw = ac ^ (ar & 3);
    const int lr = lane & 15;
    const int q  = lane >> 4;

    for (int k0 = 0; k0 < K; k0 += BK) {
        __syncthreads();
#pragma unroll
        for (int it = 0; it < 2; ++it) {
            const int row = m0 + it * 64 + ar;
            const int b = row / (Ss - 1), t = row - b * (Ss - 1);
            const int col = k0 + sw * 8;
            const bf16* gp = (col < 256)
                ? xb  + (size_t)b * (Ss * Dd) + col
                : wbb + ((size_t)(b * Ss + t)) * Dd + (col - 256);
            GL2LDS(gp, As + it * 2048 + wave * 512);
        }
        {
            const bf16* gp = W1b + (size_t)ar * K + k0 + sw * 8;
            GL2LDS(gp, Bs + wave * 512);
        }
        __syncthreads();

        bf16x8 af[4], bfv[NF];
#pragma unroll
        for (int fm = 0; fm < 4; ++fm) {
            int m = wm + fm * 16 + lr;
            af[fm] = *(const bf16x8*)(As + m * 32 + ((q ^ (m & 3)) * 8));
        }
#pragma unroll
        for (int fn = 0; fn < NF; ++fn) {
            int n = wn + fn * 16 + lr;
            bfv[fn] = *(const bf16x8*)(Bs + n * 32 + ((q ^ (n & 3)) * 8));
        }
#pragma unroll
        for (int fm = 0; fm < 4; ++fm)
#pragma unroll
            for (int fn = 0; fn < NF; ++fn)
                acc[fm][fn] = __builtin_amdgcn_mfma_f32_16x16x32_bf16(
                    af[fm], bfv[fn], acc[fm][fn], 0, 0, 0);
    }

    const int rbase = q * 4;
#pragma unroll
    for (int fn = 0; fn < NF; ++fn) {
        const int col = wn + fn * 16 + lr;
        const float bb = b1[col];
#pragma unroll
        for (int fm = 0; fm < 4; ++fm) {
            f32x4 v = acc[fm][fn];
#pragma unroll
            for (int r = 0; r < 4; ++r) {
                const int row = m0 + wm + fm * 16 + rbase + r;
                H1[(size_t)row * 64 + col] = tanhf(v[r] + bb);
            }
        }
    }
}

// ---------------- fused LSTM recurrence (r7 config + pacc padding) ---------
// 64 blocks x 512 threads. Block (bm = blockIdx&15, bd = blockIdx>>4):
// batch rows bm*16..+15, hidden quarter [bd*64,+64). Wave w: kh = w>>2
// (K-half), ct = w&3 (16-col tile); weights 4x4 frags = 64 VGPR (resident,
// r7 VGPR=88). pacc padded [16][17] (r7's [16][16] was a 4-way bank
// conflict, 1.25M). Exchange = r7's measured-best flag protocol (r8's
// tagged data-poll regressed: LLC contention). Preact prefetch in poll
// window.
__global__ __launch_bounds__(512, 2) void lstm_quad(
    const bf16* __restrict__ Whhb,    // (1024 x 256) N x K
    const float* __restrict__ gates,  // (B*S x 1024) x@Wih^T+bih+bhh
    bf16* __restrict__ rnnb,          // (B*S x 256) h outputs + exchange
    unsigned* __restrict__ bar)       // flags: bar[(bm*4+bd)*32]
{
    __shared__ bf16 hb0[16 * 256];
    __shared__ bf16 hb1[16 * 256];
    __shared__ float pacc[4][4][16][17];   // padded: kills 4-way conflicts
    const int tid  = threadIdx.x;
    const int w    = tid >> 6;
    const int lane = tid & 63;
    const int lr   = lane & 15;
    const int q    = lane >> 4;
    const int bm   = blockIdx.x & 15;
    const int bd   = blockIdx.x >> 4;       // 0..3
    const int kh   = w >> 2;                // K-half
    const int ct   = w & 3;                 // col tile
    const int dg   = bd * 64 + ct * 16 + lr;

    // ---- loop-invariant Whh fragments for this K-half: 64 VGPR ----
    f32x4 wfr[4][4];
#pragma unroll
    for (int g = 0; g < 4; ++g) {
        const bf16* brow = Whhb + (size_t)(g * 256 + dg) * Dd + kh * 128 + q * 8;
#pragma unroll
        for (int kc = 0; kc < 4; ++kc)
            wfr[g][kc] = *(const f32x4*)(brow + kc * 32);
    }

    // gate-preact pointers (kh=0 lanes): rows q*4+r, col dg
    const float* gp[4];
#pragma unroll
    for (int r = 0; r < 4; ++r)
        gp[r] = gates + (size_t)(bm * 16 + q * 4 + r) * (Ss * 1024) + dg;

    // pack/store role (tid < 256): 8 B = 4 cols of one row
    const int xrow = tid >> 4, xc8 = tid & 15;
    const size_t my_base = ((size_t)(bm * 16 + xrow) * Ss) * Dd + bd * 64 + xc8 * 4;
    const int pack_off = xrow * 512 + (((bd * 8 + (xc8 >> 1)) ^ (xrow & 7)) << 4) + (xc8 & 1) * 8;

    // remote-load slots: slot A (all 512 threads), slot B (tid < 256)
    const int pA  = tid >> 8;                         // 0 or 1
    const int pdA = pA + (pA >= bd ? 1 : 0);
    const int pdB = 2 + (2 >= bd ? 1 : 0);
    const int rowA = (tid >> 4) & 15, xqA = tid & 15;
    const size_t gA = ((size_t)(bm * 16 + rowA) * Ss) * Dd + pdA * 64 + xqA * 4;
    const size_t gB = ((size_t)(bm * 16 + xrow) * Ss) * Dd + pdB * 64 + xc8 * 4;
    const int unpA = rowA * 512 + (((pdA * 8 + (xqA >> 1)) ^ (rowA & 7)) << 4) + (xqA & 1) * 8;
    const int unpB = xrow * 512 + (((pdB * 8 + (xc8 >> 1)) ^ (xrow & 7)) << 4) + (xc8 & 1) * 8;
    unsigned* myf = bar + (bm * 4 + bd) * 32;
    unsigned* pfA = bar + (bm * 4 + pdA) * 32;
    unsigned* pfB = bar + (bm * 4 + pdB) * 32;

    // elementwise LDS write offsets (kh=0 lanes): row q*4+r, col dg
    int ew_off[4];
#pragma unroll
    for (int r = 0; r < 4; ++r) {
        const int row = q * 4 + r;
        ew_off[r] = row * 512 + (((dg >> 3) ^ (row & 7)) << 4) + (dg & 7) * 2;
    }

    float c[4] = {0.f, 0.f, 0.f, 0.f};
    float gaA[4][4], gaB[4][4];   // [gate][r], double-buffered preacts
    if (kh == 0) {
#pragma unroll
        for (int r = 0; r < 4; ++r)
#pragma unroll
            for (int g = 0; g < 4; ++g) gaA[g][r] = gp[r][g * 256];
    }

#define STEP(T, GACUR, GANEXT, RD, WR, FIRST)                                   \
    {                                                                           \
        f32x4 acc[4];                                                           \
        _Pragma("unroll")                                                       \
        for (int g = 0; g < 4; ++g) acc[g] = (f32x4){0.f, 0.f, 0.f, 0.f};       \
        if (!(FIRST)) {                                                         \
            bf16x8 af[4];                                                       \
            _Pragma("unroll")                                                   \
            for (int kc = 0; kc < 4; ++kc)                                      \
                af[kc] = *(const bf16x8*)((const char*)(RD) + lr * 512          \
                         + (((kh * 16 + kc * 4 + q) ^ (lr & 7)) << 4));         \
            _Pragma("unroll")                                                   \
            for (int kc = 0; kc < 4; ++kc)                                      \
                _Pragma("unroll")                                               \
                for (int g = 0; g < 4; ++g)                                     \
                    acc[g] = __builtin_amdgcn_mfma_f32_16x16x32_bf16(           \
                        af[kc], __builtin_bit_cast(bf16x8, wfr[g][kc]),         \
                        acc[g], 0, 0, 0);                                       \
        }                                                                       \
        if (kh == 1) {                                                          \
            _Pragma("unroll")                                                   \
            for (int g = 0; g < 4; ++g)                                         \
                _Pragma("unroll")                                               \
                for (int r = 0; r < 4; ++r)                                     \
                    pacc[ct][g][q * 4 + r][lr] = acc[g][r];                     \
        }                                                                       \
        __syncthreads();  /* Ba: kh1 partials visible */                        \
        if (kh == 0) {                                                          \
            _Pragma("unroll")                                                   \
            for (int r = 0; r < 4; ++r) {                                       \
                float gi = acc[0][r] + pacc[ct][0][q * 4 + r][lr] + GACUR[0][r];\
                float gf = acc[1][r] + pacc[ct][1][q * 4 + r][lr] + GACUR[1][r];\
                float gg = acc[2][r] + pacc[ct][2][q * 4 + r][lr] + GACUR[2][r];\
                float go = acc[3][r] + pacc[ct][3][q * 4 + r][lr] + GACUR[3][r];\
                float ii  = 1.f / (1.f + expf(-gi));                            \
                float ff  = 1.f / (1.f + expf(-gf));                            \
                float g2t = tanhf(gg);                                          \
                float oo  = 1.f / (1.f + expf(-go));                            \
                c[r] = ff * c[r] + ii * g2t;                                    \
                *(bf16*)((char*)(WR) + ew_off[r]) = (bf16)(oo * tanhf(c[r]));   \
            }                                                                   \
        }                                                                       \
        __syncthreads();  /* B1: local h slice in LDS */                        \
        if (tid < 256) {                                                        \
            u64 v = *(const u64*)((const char*)(WR) + pack_off);                \
            __hip_atomic_store((u64*)(rnnb + my_base + (size_t)(T) * Dd), v,    \
                               __ATOMIC_RELAXED, __HIP_MEMORY_SCOPE_AGENT);     \
        }                                                                       \
        if ((T) != Ss - 1) {                                                    \
            __syncthreads();  /* B2: per-wave vmcnt(0) -> stores at LLC */      \
            if (tid == 0)                                                       \
                __hip_atomic_store(myf, (unsigned)((T) + 1),                    \
                                   __ATOMIC_RELAXED, __HIP_MEMORY_SCOPE_AGENT); \
            if (kh == 0) {  /* preact prefetch hides under exchange */          \
                _Pragma("unroll")                                               \
                for (int r = 0; r < 4; ++r)                                     \
                    _Pragma("unroll")                                           \
                    for (int g = 0; g < 4; ++g)                                 \
                        GANEXT[g][r] = gp[r][(size_t)((T) + 1) * 1024 + g * 256];\
            }                                                                   \
            while (__hip_atomic_load(pfA, __ATOMIC_RELAXED,                     \
                                     __HIP_MEMORY_SCOPE_AGENT)                  \
                   < (unsigned)((T) + 1)) {}                                    \
            {                                                                   \
                u64 rv = __hip_atomic_load(                                     \
                    (const u64*)(rnnb + gA + (size_t)(T) * Dd),                 \
                    __ATOMIC_RELAXED, __HIP_MEMORY_SCOPE_AGENT);                \
                *(u64*)((char*)(WR) + unpA) = rv;                               \
            }                                                                   \
            if (tid < 256) {                                                    \
                while (__hip_atomic_load(pfB, __ATOMIC_RELAXED,                 \
                                         __HIP_MEMORY_SCOPE_AGENT)              \
                       < (unsigned)((T) + 1)) {}                                \
                u64 rv = __hip_atomic_load(                                     \
                    (const u64*)(rnnb + gB + (size_t)(T) * Dd),                 \
                    __ATOMIC_RELAXED, __HIP_MEMORY_SCOPE_AGENT);                \
                *(u64*)((char*)(WR) + unpB) = rv;                               \
            }                                                                   \
            __syncthreads();  /* B4: full h_t (local+3 remote) in WR */         \
        }                                                                       \
    }

    for (int t2 = 0; t2 < Ss; t2 += 2) {
        STEP(t2,     gaA, gaB, hb1, hb0, (t2 == 0));
        STEP(t2 + 1, gaB, gaA, hb0, hb1, false);
    }
#undef STEP
}

// ---------------- fused prep: weight converts + Wdiff transpose + alpha ----
// Blocks: [0,1024) Wih cvt | [1024,2048) Whh | [2048,2304) Whk |
// [2304,2432) W1 | [2432,2496) Wdiff 32x32 transpose tiles | 2496 alpha+flags
__global__ __launch_bounds__(256) void prep_kernel(
    const float* __restrict__ Wih, bf16* __restrict__ Wihb,
    const float* __restrict__ Whh, bf16* __restrict__ Whhb,
    const float* __restrict__ Whk, bf16* __restrict__ Whkb,
    const float* __restrict__ W1,  bf16* __restrict__ W1b,
    const float* __restrict__ Wdiff, bf16* __restrict__ WdTb,
    const int* __restrict__ tdiff, float* __restrict__ salpha,
    float* __restrict__ sbeta, unsigned* __restrict__ bar)
{
    __shared__ float t[32][33];
    int bx = blockIdx.x;
    const int tid = threadIdx.x;
    if (bx < 1024) { int i = bx * 256 + tid; Wihb[i] = (bf16)Wih[i]; return; }
    bx -= 1024;
    if (bx < 1024) { int i = bx * 256 + tid; Whhb[i] = (bf16)Whh[i]; return; }
    bx -= 1024;
    if (bx < 256)  { int i = bx * 256 + tid; Whkb[i] = (bf16)Whk[i]; return; }
    bx -= 256;
    if (bx < 128)  { int i = bx * 256 + tid; W1b[i]  = (bf16)W1[i];  return; }
    bx -= 128;
    if (bx < 64) {
        const int c0 = (bx & 7) * 32, r0 = (bx >> 3) * 32;
        const int tx = tid & 31, ty = tid >> 5;
        for (int i = ty; i < 32; i += 8)
            t[i][tx] = Wdiff[(size_t)(r0 + i) * 256 + c0 + tx];
        __syncthreads();
        for (int i = ty; i < 32; i += 8)
            WdTb[(size_t)(c0 + i) * 256 + r0 + tx] = (bf16)t[tx][i];
        return;
    }
    // alpha + barrier-flag init (64 flag slots x 32 words = 2048)
#pragma unroll
    for (int j = 0; j < 8; ++j) bar[tid * 8 + j] = 0u;
    const int tt = tdiff[tid];
    const float step = (0.02f - 1e-4f) / 999.f;
    float prod = 1.f;
    for (int j = 0; j <= tt; ++j) prod *= (1.f - (1e-4f + j * step));
    salpha[tid] = sqrtf(prod);
    sbeta[tid]  = sqrtf(fmaxf(1.f - prod, 0.f));
}

// ---------------- embedding gather-sum (fp32 + bf16 outputs) ----------------
__global__ __launch_bounds__(256) void embed_kernel(
    const int* __restrict__ seqs, const float* __restrict__ emb,
    float* __restrict__ x, bf16* __restrict__ xb)
{
    __shared__ int idx[Cc];
    const int bs = blockIdx.x;
    const int tid = threadIdx.x;
    if (tid < Cc) idx[tid] = seqs[(size_t)bs * Cc + tid];
    __syncthreads();
    float s = 0.f;
#pragma unroll 8
    for (int c = 0; c < Cc; ++c) s += emb[(size_t)idx[c] * Dd + tid];
    x[(size_t)bs * Dd + tid]  = s;
    xb[(size_t)bs * Dd + tid] = (bf16)s;
}

// ---------------- fused attn logits + softmax + apply + diffusion + copy ---
// Per (b,s) block: wave 0 recomputes the 2-logit reduction for r=b*49+s-1
// (identical arithmetic/order to the old attn2), softmax in LDS, then all
// 256 threads apply attention, diffusion, and the noise passthrough.
__global__ __launch_bounds__(256) void attn_diff_kernel(
    const float* __restrict__ x, const float* __restrict__ w,
    const float* __restrict__ H1, const float* __restrict__ W2,
    const float* __restrict__ b2, const float* __restrict__ noise,
    const float* __restrict__ temb, const int* __restrict__ tdiff,
    const float* __restrict__ salpha, const float* __restrict__ sbeta,
    float* __restrict__ aligned, bf16* __restrict__ tmpb,
    float* __restrict__ noise_out)
{
    __shared__ float sa[2];
    const int bs = blockIdx.x;
    const int b = bs / Ss, s = bs % Ss;
    const int d = threadIdx.x;
    if (s > 0 && threadIdx.x < 64) {
        const int r = b * (Ss - 1) + (s - 1);
        const int j = threadIdx.x;
        float h = H1[(size_t)r * 64 + j];
        float v0 = h * W2[j];
        float v1 = h * W2[64 + j];
#pragma unroll
        for (int off = 32; off; off >>= 1) { v0 += __shfl_down(v0, off); v1 += __shfl_down(v1, off); }
        if (j == 0) {
            float z0 = v0 + b2[0], z1 = v1 + b2[1];
            float m = fmaxf(z0, z1);
            float e0 = expf(z0 - m), e1 = expf(z1 - m);
            float inv = 1.f / (e0 + e1);
            sa[0] = e0 * inv;
            sa[1] = e1 * inv;
        }
    }
    __syncthreads();
    const float ek = x[((size_t)b * Ss) * Dd + d];
    float v;
    if (s == 0) {
        v = ek;
    } else {
        v = ek * sa[0] + w[((size_t)b * Ss + s - 1) * Dd + d] * sa[1];
    }
    const size_t i = (size_t)bs * Dd + d;
    aligned[i] = v;
    const int t = tdiff[b];
    tmpb[i] = (bf16)(v * salpha[b] + noise[i] * sbeta[b] + temb[(size_t)t * Dd + d]);
    noise_out[i] = noise[i];   // passthrough output (replaces the D2D memcpy)
}

// ---------------- pooled 2-class heads ----------------
__device__ inline void pool_reduce_write(float m, const float* __restrict__ Wout,
                                         const float* __restrict__ bout,
                                         float* __restrict__ outp, int b,
                                         float* r0, float* r1)
{
    float v0 = m * Wout[threadIdx.x];
    float v1 = m * Wout[Dd + threadIdx.x];
#pragma unroll
    for (int off = 32; off; off >>= 1) { v0 += __shfl_down(v0, off); v1 += __shfl_down(v1, off); }
    const int lane = threadIdx.x & 63, wv = threadIdx.x >> 6;
    if (lane == 0) { r0[wv] = v0; r1[wv] = v1; }
    __syncthreads();
    if (threadIdx.x == 0) {
        outp[b * 2 + 0] = r0[0] + r0[1] + r0[2] + r0[3] + bout[0];
        outp[b * 2 + 1] = r1[0] + r1[1] + r1[2] + r1[3] + bout[1];
    }
}

__global__ __launch_bounds__(256) void pool_x_kernel(
    const float* __restrict__ x, const float* __restrict__ Wout,
    const float* __restrict__ bout, float* __restrict__ outp)
{
    __shared__ float r0[4], r1[4];
    const int b = blockIdx.x, d = threadIdx.x;
    float m = -INFINITY;
    for (int s = 0; s < Ss; ++s) m = fmaxf(m, x[((size_t)b * Ss + s) * Dd + d]);
    pool_reduce_write(m, Wout, bout, outp, b, r0, r1);
}

__global__ __launch_bounds__(256) void gen_pool_kernel(
    const float* __restrict__ aligned, const float* __restrict__ noise,
    const float* __restrict__ pred, const float* __restrict__ Wout,
    const float* __restrict__ bout, float* __restrict__ outp)
{
    __shared__ float r0[4], r1[4];
    const int b = blockIdx.x, d = threadIdx.x;
    float m = -INFINITY;
    for (int s = 0; s < Ss; ++s) {
        const size_t i = ((size_t)b * Ss + s) * Dd + d;
        m = fmaxf(m, aligned[i] + noise[i] - pred[i]);
    }
    pool_reduce_write(m, Wout, bout, outp, b, r0, r1);
}

// ---------------- host ----------------
extern "C" void kernel_launch(void* const* d_in, const int* in_sizes, int n_in,
                              void* d_out, int out_size, void* d_ws, size_t ws_size,
                              hipStream_t stream)
{
    const int*   seqs  = (const int*)d_in[0];
    const int*   tdiff = (const int*)d_in[5];
    const float* noise = (const float*)d_in[6];
    const float* emb   = (const float*)d_in[7];
    const float* Wih   = (const float*)d_in[8];
    const float* Whh   = (const float*)d_in[9];
    const float* bih   = (const float*)d_in[10];
    const float* bhh   = (const float*)d_in[11];
    const float* Whk   = (const float*)d_in[12];
    const float* bhk   = (const float*)d_in[13];
    const float* W1    = (const float*)d_in[14];
    const float* b1    = (const float*)d_in[15];
    const float* W2    = (const float*)d_in[16];
    const float* b2    = (const float*)d_in[17];
    const float* Wdiff = (const float*)d_in[18];
    const float* bdiff = (const float*)d_in[19];
    const float* temb  = (const float*)d_in[20];
    const float* Wout  = (const float*)d_in[21];
    const float* bout  = (const float*)d_in[22];

    float* outp = (float*)d_out;
    char*  wsb  = (char*)d_ws;

    float* gates   = (float*)(wsb + OFFB_GATES);
    float* aligned = (float*)(wsb + OFFB_ALIGNED);
    bf16*  wbb     = (bf16*) (wsb + OFFB_WBB);
    bf16*  tmpb    = (bf16*) (wsb + OFFB_TMPB);
    float* H1      = (float*)(wsb + OFFB_H1);
    float* x       = (float*)(wsb + OFFB_X);
    bf16*  xb      = (bf16*) (wsb + OFFB_XB);
    bf16*  rnnb    = (bf16*) (wsb + OFFB_RNNB);
    float* wbuf    = (float*)(wsb + OFFB_W);
    unsigned* bar  = (unsigned*)(wsb + OFFB_BAR);
    bf16*  Wihb    = (bf16*) (wsb + OFFB_WIHB);
    bf16*  Whhb    = (bf16*) (wsb + OFFB_WHHB);
    bf16*  Whkb    = (bf16*) (wsb + OFFB_WHKB);
    bf16*  W1b     = (bf16*) (wsb + OFFB_W1B);
    bf16*  WdTb    = (bf16*) (wsb + OFFB_WDTB);
    float* salpha  = (float*)(wsb + OFFB_SALPHA);
    float* sbeta   = (float*)(wsb + OFFB_SBETA);

    float* pred_out  = outp + 1024;                        // (B,S,D)
    float* noise_out = outp + 1024 + (size_t)Bb * Ss * Dd; // (B,S,D)

    // fused prep: all weight converts + Wdiff transpose + alpha + flag init
    prep_kernel<<<2497, 256, 0, stream>>>(Wih, Wihb, Whh, Whhb, Whk, Whkb,
                                          W1, W1b, Wdiff, WdTb,
                                          tdiff, salpha, sbeta, bar);

    // x = emb[seqs].sum(axis=2)  (fp32 + bf16)
    embed_kernel<<<Bb * Ss, 256, 0, stream>>>(seqs, emb, x, xb);

    // pool_x head (only needs x)
    pool_x_kernel<<<Bb, 256, 0, stream>>>(x, Wout, bout, outp);

    // gates_pre = x @ Wih^T + bih + bhh : (12800 x 1024), K=256
    mfma_gemm<128, 128, 0><<<dim3(100, 8), 256, 0, stream>>>(
        xb, 256, Wihb, 256, bih, bhh, gates, nullptr, 1024, 256);

    // LSTM recurrence: ONE launch, 64 blocks, r7 flag exchange
    lstm_quad<<<64, 512, 0, stream>>>(Whhb, gates, rnnb, bar);

    // w = rnn @ Whk^T + bhk : fp32 wbuf + bf16 wbb (feeds fused-cat H1 GEMM)
    mfma_gemm<128, 128, 0><<<dim3(100, 2), 256, 0, stream>>>(
        rnnb, 256, Whkb, 256, bhk, nullptr, wbuf, wbb, 256, 256);

    // H1 = tanh(cat @ W1^T + b1), cat built on the fly from xb/wbb
    h1_gemm<<<dim3(98, 1), 256, 0, stream>>>(xb, wbb, W1b, b1, H1);

    // fused: attn logits+softmax, apply, diffusion elementwise, noise copy
    attn_diff_kernel<<<Bb * Ss, 256, 0, stream>>>(
        x, wbuf, H1, W2, b2, noise, temb, tdiff, salpha, sbeta,
        aligned, tmpb, noise_out);

    // predicted_noise = tmp @ Wdiff + bdiff -> d_out
    mfma_gemm<128, 128, 0><<<dim3(100, 2), 256, 0, stream>>>(
        tmpb, 256, WdTb, 256, bdiff, nullptr, pred_out, nullptr, 256, 256);

    // gen_pool head: max_s(aligned + noise - pred) @ Wout^T + bout
    gen_pool_kernel<<<Bb, 256, 0, stream>>>(aligned, noise, pred_out, Wout, bout, outp + 512);
}